// Round 1
// baseline (1678.100 us; speedup 1.0000x reference)
//
#include <hip/hip_runtime.h>
#include <cstdint>

#define D128 128

// ---------------- graph prep ----------------

__global__ void k_init(float* __restrict__ deg, int* __restrict__ cnt,
                       int* __restrict__ cursor, int n) {
  int i = blockIdx.x * blockDim.x + threadIdx.x;
  if (i < n) { deg[i] = 1.0f; cnt[i] = 0; cursor[i] = 0; }
}

__global__ void k_deg_hist(const int* __restrict__ ei, const float* __restrict__ ew,
                           float* __restrict__ deg, int* __restrict__ cnt, int E) {
  int e = blockIdx.x * blockDim.x + threadIdx.x;
  if (e >= E) return;
  int c = ei[E + e];
  atomicAdd(&deg[c], ew[e]);
  atomicAdd(&cnt[c], 1);
}

__global__ void k_dinv(float* __restrict__ dinv, int n) {
  int i = blockIdx.x * blockDim.x + threadIdx.x;
  if (i < n) dinv[i] = rsqrtf(dinv[i]);  // deg >= 1 always (self-loop)
}

// exclusive scan of cnt[n] -> rowptr, 1024 elems/block
__global__ void k_scan1(const int* __restrict__ cnt, int* __restrict__ out,
                        int* __restrict__ bsum, int n) {
  __shared__ int s[256];
  int t = threadIdx.x;
  int base = blockIdx.x * 1024 + t * 4;
  int c0 = (base + 0 < n) ? cnt[base + 0] : 0;
  int c1 = (base + 1 < n) ? cnt[base + 1] : 0;
  int c2 = (base + 2 < n) ? cnt[base + 2] : 0;
  int c3 = (base + 3 < n) ? cnt[base + 3] : 0;
  int tot = c0 + c1 + c2 + c3;
  s[t] = tot;
  __syncthreads();
  for (int off = 1; off < 256; off <<= 1) {
    int v = (t >= off) ? s[t - off] : 0;
    __syncthreads();
    s[t] += v;
    __syncthreads();
  }
  int excl = (t == 0) ? 0 : s[t - 1];
  if (base + 0 < n) out[base + 0] = excl;
  if (base + 1 < n) out[base + 1] = excl + c0;
  if (base + 2 < n) out[base + 2] = excl + c0 + c1;
  if (base + 3 < n) out[base + 3] = excl + c0 + c1 + c2;
  if (t == 255) bsum[blockIdx.x] = s[255];
}

__global__ void k_scan2(int* __restrict__ bsum, int nb) {
  __shared__ int s[64];
  int t = threadIdx.x;
  if (t < nb) s[t] = bsum[t];
  __syncthreads();
  if (t == 0) {
    int acc = 0;
    for (int i = 0; i < nb; ++i) { int v = s[i]; s[i] = acc; acc += v; }
  }
  __syncthreads();
  if (t < nb) bsum[t] = s[t];
}

__global__ void k_scan3(int* __restrict__ rowptr, const int* __restrict__ bsum,
                        int n, int E) {
  int i = blockIdx.x * blockDim.x + threadIdx.x;
  if (i < n) rowptr[i] += bsum[i >> 10];
  if (i == 0) rowptr[n] = E;
}

__global__ void k_scatter(const int* __restrict__ ei, const float* __restrict__ ew,
                          const float* __restrict__ dinv, const int* __restrict__ rowptr,
                          int* __restrict__ cursor, int* __restrict__ esrc,
                          float* __restrict__ enorm, int E) {
  int e = blockIdx.x * blockDim.x + threadIdx.x;
  if (e >= E) return;
  int r = ei[e];
  int c = ei[E + e];
  int p = rowptr[c] + atomicAdd(&cursor[c], 1);
  esrc[p] = r;
  enorm[p] = dinv[r] * ew[e] * dinv[c];
}

// ---------------- GEMM: C[:, coff:coff+128] = A0@B0 + A1@B1 ----------------
// A0,A1: [nrows x 128] row-major. B0,B1: [128 x 128] row-major.
// BM=128, BN=128, BK=32. 256 threads, 8x8 per thread.

__global__ __launch_bounds__(256)
void k_gemm_pair(const float* __restrict__ A0, const float* __restrict__ A1,
                 const float* __restrict__ B0, const float* __restrict__ B1,
                 float* __restrict__ C, int cstride, int coff, int nrows) {
  __shared__ float As[32][128];
  __shared__ float Bs[32][128];
  int t = threadIdx.x;
  int row0 = blockIdx.x * 128;

  float acc[8][8];
#pragma unroll
  for (int i = 0; i < 8; ++i)
#pragma unroll
    for (int j = 0; j < 8; ++j) acc[i][j] = 0.0f;

  // A load mapping: thread t loads row (t>>1), k-half (t&1)*16 .. +15  (4 float4)
  int a_row = t >> 1;
  int a_k0 = (t & 1) * 16;
  // B load mapping: thread t loads k-row (t>>3), cols (t&7)*16 .. +15 (4 float4)
  int b_k = t >> 3;
  int b_n0 = (t & 7) * 16;

  int rm = (t >> 4) * 8;
  int rn = (t & 15) * 8;

  const float* Ap[2] = {A0, A1};
  const float* Bp[2] = {B0, B1};

  for (int s = 0; s < 2; ++s) {
    const float* A = Ap[s];
    const float* B = Bp[s];
    for (int kt = 0; kt < 128; kt += 32) {
      __syncthreads();
      // load A tile (transposed into LDS: As[k][m])
      int gr = row0 + a_row;
      float4 av[4];
      if (gr < nrows) {
        const float* ap = &A[(size_t)gr * D128 + kt + a_k0];
#pragma unroll
        for (int q = 0; q < 4; ++q) av[q] = *(const float4*)(ap + q * 4);
      } else {
#pragma unroll
        for (int q = 0; q < 4; ++q) av[q] = make_float4(0.f, 0.f, 0.f, 0.f);
      }
#pragma unroll
      for (int q = 0; q < 4; ++q) {
        As[a_k0 + q * 4 + 0][a_row] = av[q].x;
        As[a_k0 + q * 4 + 1][a_row] = av[q].y;
        As[a_k0 + q * 4 + 2][a_row] = av[q].z;
        As[a_k0 + q * 4 + 3][a_row] = av[q].w;
      }
      // load B tile
      {
        const float* bp = &B[(size_t)(kt + b_k) * D128 + b_n0];
#pragma unroll
        for (int q = 0; q < 4; ++q)
          *(float4*)&Bs[b_k][b_n0 + q * 4] = *(const float4*)(bp + q * 4);
      }
      __syncthreads();
#pragma unroll
      for (int k = 0; k < 32; ++k) {
        float4 af0 = *(const float4*)&As[k][rm];
        float4 af1 = *(const float4*)&As[k][rm + 4];
        float4 bf0 = *(const float4*)&Bs[k][rn];
        float4 bf1 = *(const float4*)&Bs[k][rn + 4];
        float a[8] = {af0.x, af0.y, af0.z, af0.w, af1.x, af1.y, af1.z, af1.w};
        float b[8] = {bf0.x, bf0.y, bf0.z, bf0.w, bf1.x, bf1.y, bf1.z, bf1.w};
#pragma unroll
        for (int i = 0; i < 8; ++i)
#pragma unroll
          for (int j = 0; j < 8; ++j) acc[i][j] += a[i] * b[j];
      }
    }
  }

#pragma unroll
  for (int i = 0; i < 8; ++i) {
    int gr = row0 + rm + i;
    if (gr < nrows) {
      float4 v0 = make_float4(acc[i][0], acc[i][1], acc[i][2], acc[i][3]);
      float4 v1 = make_float4(acc[i][4], acc[i][5], acc[i][6], acc[i][7]);
      float* cp = &C[(size_t)gr * cstride + coff + rn];
      *(float4*)cp = v0;
      *(float4*)(cp + 4) = v1;
    }
  }
}

// ---------------- aggregation: out[n] = dinv[n]^2*u[n] + sum_e norm*u[src] ----
// one block per node, blockDim = W (128 or 256)

template <int W>
__global__ void k_agg(const float* __restrict__ u, float* __restrict__ out,
                      const int* __restrict__ rowptr, const int* __restrict__ esrc,
                      const float* __restrict__ enorm, const float* __restrict__ dinv) {
  __shared__ int ss[128];
  __shared__ float snm[128];
  int n = blockIdx.x;
  int t = threadIdx.x;
  float dv = dinv[n];
  float acc = dv * dv * u[(size_t)n * W + t];
  int e0 = rowptr[n], e1 = rowptr[n + 1];
  for (int base = e0; base < e1; base += 128) {
    int m = min(128, e1 - base);
    __syncthreads();
    if (t < m) {
      ss[t] = esrc[base + t];
      snm[t] = enorm[base + t];
    }
    __syncthreads();
#pragma unroll 4
    for (int j = 0; j < m; ++j) acc += snm[j] * u[(size_t)ss[j] * W + t];
  }
  out[(size_t)n * W + t] = acc;
}

// ---------------- activations ----------------

__global__ void k_act1(const float* __restrict__ az, const float* __restrict__ hl,
                       const float* __restrict__ bxz, const float* __restrict__ bhz,
                       const float* __restrict__ bxr, const float* __restrict__ bhr,
                       float* __restrict__ zbuf, float* __restrict__ rhbuf, int n) {
  int i = blockIdx.x * blockDim.x + threadIdx.x;
  if (i >= n * D128) return;
  int nd = i >> 7, t = i & 127;
  float zz = az[(size_t)nd * 256 + t] + bxz[t] + bhz[t];
  float rr = az[(size_t)nd * 256 + 128 + t] + bxr[t] + bhr[t];
  float z = 1.0f / (1.0f + __expf(-zz));
  float r = 1.0f / (1.0f + __expf(-rr));
  zbuf[i] = z;
  rhbuf[i] = r * hl[i];
}

__global__ void k_act2(const float* __restrict__ av, const float* __restrict__ hl,
                       const float* __restrict__ bxh, const float* __restrict__ bhh,
                       const float* __restrict__ zbuf, float* __restrict__ out, int n) {
  int i = blockIdx.x * blockDim.x + threadIdx.x;
  if (i >= n * D128) return;
  int t = i & 127;
  float ht = tanhf(av[i] + bxh[t] + bhh[t]);
  float z = zbuf[i];
  out[i] = z * hl[i] + (1.0f - z) * ht;
}

// ---------------- host ----------------

static inline char* align16(char* p) {
  return (char*)(((uintptr_t)p + 15) & ~(uintptr_t)15);
}

extern "C" void kernel_launch(void* const* d_in, const int* in_sizes, int n_in,
                              void* d_out, int out_size, void* d_ws, size_t ws_size,
                              hipStream_t stream) {
  const float* x = (const float*)d_in[0];
  const int* ei = (const int*)d_in[1];
  const float* ew = (const float*)d_in[2];
  const float* h = (const float*)d_in[3];
  const float* Wxz = (const float*)d_in[4];
  const float* bxz = (const float*)d_in[5];
  const float* Whz = (const float*)d_in[6];
  const float* bhz = (const float*)d_in[7];
  const float* Wxr = (const float*)d_in[8];
  const float* bxr = (const float*)d_in[9];
  const float* Whr = (const float*)d_in[10];
  const float* bhr = (const float*)d_in[11];
  const float* Wxh = (const float*)d_in[12];
  const float* bxh = (const float*)d_in[13];
  const float* Whh = (const float*)d_in[14];
  const float* bhh = (const float*)d_in[15];
  float* out = (float*)d_out;

  const int N = in_sizes[0] / D128;
  const int E = in_sizes[2];
  const int L = in_sizes[3] / (N * D128);

  char* w = (char*)d_ws;
  float* dinv = (float*)w;  w += (size_t)N * 4;           w = align16(w);
  int* cnt = (int*)w;       w += (size_t)N * 4;           w = align16(w);
  int* rowptr = (int*)w;    w += (size_t)(N + 1) * 4;     w = align16(w);
  int* cursor = (int*)w;    w += (size_t)N * 4;           w = align16(w);
  int* bsum = (int*)w;      w += 64 * 4;                  w = align16(w);
  int* esrc = (int*)w;      w += (size_t)E * 4;           w = align16(w);
  float* enorm = (float*)w; w += (size_t)E * 4;           w = align16(w);
  float* bufA = (float*)w;  w += (size_t)N * 256 * 4;     w = align16(w);
  float* bufB = (float*)w;  w += (size_t)N * 256 * 4;     w = align16(w);
  float* zbuf = (float*)w;  w += (size_t)N * D128 * 4;    w = align16(w);
  float* rhbuf = (float*)w; w += (size_t)N * D128 * 4;    w = align16(w);

  int gN = (N + 255) / 256;
  int gE = (E + 255) / 256;
  int nScanBlk = (N + 1023) / 1024;
  int gGemm = (N + 127) / 128;
  int gAct = (N * D128 + 255) / 256;

  k_init<<<gN, 256, 0, stream>>>(dinv, cnt, cursor, N);
  k_deg_hist<<<gE, 256, 0, stream>>>(ei, ew, dinv, cnt, E);
  k_dinv<<<gN, 256, 0, stream>>>(dinv, N);
  k_scan1<<<nScanBlk, 256, 0, stream>>>(cnt, rowptr, bsum, N);
  k_scan2<<<1, 64, 0, stream>>>(bsum, nScanBlk);
  k_scan3<<<gN, 256, 0, stream>>>(rowptr, bsum, N, E);
  k_scatter<<<gE, 256, 0, stream>>>(ei, ew, dinv, rowptr, cursor, esrc, enorm, E);

  const float* xin = x;
  for (int l = 0; l < L; ++l) {
    const float* hl = h + (size_t)l * N * D128;
    const float* Wxz_l = Wxz + (size_t)l * D128 * D128;
    const float* Whz_l = Whz + (size_t)l * D128 * D128;
    const float* Wxr_l = Wxr + (size_t)l * D128 * D128;
    const float* Whr_l = Whr + (size_t)l * D128 * D128;
    const float* Wxh_l = Wxh + (size_t)l * D128 * D128;
    const float* Whh_l = Whh + (size_t)l * D128 * D128;
    const float* bxz_l = bxz + (size_t)l * D128;
    const float* bhz_l = bhz + (size_t)l * D128;
    const float* bxr_l = bxr + (size_t)l * D128;
    const float* bhr_l = bhr + (size_t)l * D128;
    const float* bxh_l = bxh + (size_t)l * D128;
    const float* bhh_l = bhh + (size_t)l * D128;

    // stage 1: z,r pre-activations: bufA[:,0:128]=xin@Wxz+hl@Whz, [:,128:256]=xin@Wxr+hl@Whr
    k_gemm_pair<<<gGemm, 256, 0, stream>>>(xin, hl, Wxz_l, Whz_l, bufA, 256, 0, N);
    k_gemm_pair<<<gGemm, 256, 0, stream>>>(xin, hl, Wxr_l, Whr_l, bufA, 256, 128, N);
    k_agg<256><<<N, 256, 0, stream>>>(bufA, bufB, rowptr, esrc, enorm, dinv);
    k_act1<<<gAct, 256, 0, stream>>>(bufB, hl, bxz_l, bhz_l, bxr_l, bhr_l, zbuf, rhbuf, N);

    // stage 2: v = xin@Wxh + (r*h)@Whh  -> aggregate -> ht, ho
    k_gemm_pair<<<gGemm, 256, 0, stream>>>(xin, rhbuf, Wxh_l, Whh_l, bufA, 128, 0, N);
    k_agg<128><<<N, 128, 0, stream>>>(bufA, bufB, rowptr, esrc, enorm, dinv);
    float* ho = out + (size_t)l * N * D128;
    k_act2<<<gAct, 256, 0, stream>>>(bufB, hl, bxh_l, bhh_l, zbuf, ho, N);
    xin = ho;
  }
}

// Round 2
// 1114.833 us; speedup vs baseline: 1.5052x; 1.5052x over previous
//
#include <hip/hip_runtime.h>
#include <cstdint>

#define D128 128

// ---------------- helpers ----------------

static __device__ __forceinline__ unsigned short f2bf(float x) {
  unsigned int u = __float_as_uint(x);
  unsigned int r = (u + 0x7FFFu + ((u >> 16) & 1u)) >> 16;
  return (unsigned short)r;
}
static __device__ __forceinline__ float bf_lo(unsigned int v) {
  return __uint_as_float(v << 16);
}
static __device__ __forceinline__ float bf_hi(unsigned int v) {
  return __uint_as_float(v & 0xFFFF0000u);
}
static __device__ __forceinline__ float sigf(float x) {
  return 1.0f / (1.0f + __expf(-x));
}

// ---------------- graph prep ----------------

__global__ void k_init(float* __restrict__ deg, int* __restrict__ cnt,
                       int* __restrict__ cursor, int n) {
  int i = blockIdx.x * blockDim.x + threadIdx.x;
  if (i < n) { deg[i] = 1.0f; cnt[i] = 0; cursor[i] = 0; }
}

__global__ void k_deg_hist(const int* __restrict__ ei, const float* __restrict__ ew,
                           float* __restrict__ deg, int* __restrict__ cnt, int E) {
  int e = blockIdx.x * blockDim.x + threadIdx.x;
  if (e >= E) return;
  int c = ei[E + e];
  atomicAdd(&deg[c], ew[e]);
  atomicAdd(&cnt[c], 1);
}

__global__ void k_dinv(float* __restrict__ dinv, int n) {
  int i = blockIdx.x * blockDim.x + threadIdx.x;
  if (i < n) dinv[i] = rsqrtf(dinv[i]);  // deg >= 1 always (self-loop)
}

__global__ void k_scan1(const int* __restrict__ cnt, int* __restrict__ out,
                        int* __restrict__ bsum, int n) {
  __shared__ int s[256];
  int t = threadIdx.x;
  int base = blockIdx.x * 1024 + t * 4;
  int c0 = (base + 0 < n) ? cnt[base + 0] : 0;
  int c1 = (base + 1 < n) ? cnt[base + 1] : 0;
  int c2 = (base + 2 < n) ? cnt[base + 2] : 0;
  int c3 = (base + 3 < n) ? cnt[base + 3] : 0;
  int tot = c0 + c1 + c2 + c3;
  s[t] = tot;
  __syncthreads();
  for (int off = 1; off < 256; off <<= 1) {
    int v = (t >= off) ? s[t - off] : 0;
    __syncthreads();
    s[t] += v;
    __syncthreads();
  }
  int excl = (t == 0) ? 0 : s[t - 1];
  if (base + 0 < n) out[base + 0] = excl;
  if (base + 1 < n) out[base + 1] = excl + c0;
  if (base + 2 < n) out[base + 2] = excl + c0 + c1;
  if (base + 3 < n) out[base + 3] = excl + c0 + c1 + c2;
  if (t == 255) bsum[blockIdx.x] = s[255];
}

__global__ void k_scan2(int* __restrict__ bsum, int nb) {
  __shared__ int s[64];
  int t = threadIdx.x;
  if (t < nb) s[t] = bsum[t];
  __syncthreads();
  if (t == 0) {
    int acc = 0;
    for (int i = 0; i < nb; ++i) { int v = s[i]; s[i] = acc; acc += v; }
  }
  __syncthreads();
  if (t < nb) bsum[t] = s[t];
}

__global__ void k_scan3(int* __restrict__ rowptr, const int* __restrict__ bsum,
                        int n, int E) {
  int i = blockIdx.x * blockDim.x + threadIdx.x;
  if (i < n) rowptr[i] += bsum[i >> 10];
  if (i == 0) rowptr[n] = E;
}

__global__ void k_scatter(const int* __restrict__ ei, const float* __restrict__ ew,
                          const float* __restrict__ dinv, const int* __restrict__ rowptr,
                          int* __restrict__ cursor, int2* __restrict__ epk, int E) {
  int e = blockIdx.x * blockDim.x + threadIdx.x;
  if (e >= E) return;
  int r = ei[e];
  int c = ei[E + e];
  int p = rowptr[c] + atomicAdd(&cursor[c], 1);
  float nm = dinv[r] * ew[e] * dinv[c];
  epk[p] = make_int2(r, __float_as_int(nm));
}

// ---------------- GEMM: C[:, coff:coff+128] = A0@B0 + A1@B1 (bf16 out) -------
// A0,A1: [nrows x 128] fp32 row-major. B0,B1: [128 x 128] fp32 row-major.
// BM=128, BN=128, BK=32. 256 threads, 8x8 per thread. C is packed bf16,
// cstride in ELEMENTS (256 or 128).

__global__ __launch_bounds__(256)
void k_gemm_pair(const float* __restrict__ A0, const float* __restrict__ A1,
                 const float* __restrict__ B0, const float* __restrict__ B1,
                 unsigned short* __restrict__ C, int cstride, int coff, int nrows) {
  __shared__ float As[32][128];
  __shared__ float Bs[32][128];
  int t = threadIdx.x;
  int row0 = blockIdx.x * 128;

  float acc[8][8];
#pragma unroll
  for (int i = 0; i < 8; ++i)
#pragma unroll
    for (int j = 0; j < 8; ++j) acc[i][j] = 0.0f;

  int a_row = t >> 1;
  int a_k0 = (t & 1) * 16;
  int b_k = t >> 3;
  int b_n0 = (t & 7) * 16;

  int rm = (t >> 4) * 8;
  int rn = (t & 15) * 8;

  const float* Ap[2] = {A0, A1};
  const float* Bp[2] = {B0, B1};

  for (int s = 0; s < 2; ++s) {
    const float* A = Ap[s];
    const float* B = Bp[s];
    for (int kt = 0; kt < 128; kt += 32) {
      __syncthreads();
      int gr = row0 + a_row;
      float4 av[4];
      if (gr < nrows) {
        const float* ap = &A[(size_t)gr * D128 + kt + a_k0];
#pragma unroll
        for (int q = 0; q < 4; ++q) av[q] = *(const float4*)(ap + q * 4);
      } else {
#pragma unroll
        for (int q = 0; q < 4; ++q) av[q] = make_float4(0.f, 0.f, 0.f, 0.f);
      }
#pragma unroll
      for (int q = 0; q < 4; ++q) {
        As[a_k0 + q * 4 + 0][a_row] = av[q].x;
        As[a_k0 + q * 4 + 1][a_row] = av[q].y;
        As[a_k0 + q * 4 + 2][a_row] = av[q].z;
        As[a_k0 + q * 4 + 3][a_row] = av[q].w;
      }
      {
        const float* bp = &B[(size_t)(kt + b_k) * D128 + b_n0];
#pragma unroll
        for (int q = 0; q < 4; ++q)
          *(float4*)&Bs[b_k][b_n0 + q * 4] = *(const float4*)(bp + q * 4);
      }
      __syncthreads();
#pragma unroll
      for (int k = 0; k < 32; ++k) {
        float4 af0 = *(const float4*)&As[k][rm];
        float4 af1 = *(const float4*)&As[k][rm + 4];
        float4 bf0 = *(const float4*)&Bs[k][rn];
        float4 bf1 = *(const float4*)&Bs[k][rn + 4];
        float a[8] = {af0.x, af0.y, af0.z, af0.w, af1.x, af1.y, af1.z, af1.w};
        float b[8] = {bf0.x, bf0.y, bf0.z, bf0.w, bf1.x, bf1.y, bf1.z, bf1.w};
#pragma unroll
        for (int i = 0; i < 8; ++i)
#pragma unroll
          for (int j = 0; j < 8; ++j) acc[i][j] += a[i] * b[j];
      }
    }
  }

#pragma unroll
  for (int i = 0; i < 8; ++i) {
    int gr = row0 + rm + i;
    if (gr < nrows) {
      unsigned short hb[8];
#pragma unroll
      for (int j = 0; j < 8; ++j) hb[j] = f2bf(acc[i][j]);
      *(uint4*)&C[(size_t)gr * cstride + coff + rn] = *(const uint4*)hb;
    }
  }
}

// ---------------- fused aggregation + activation ----------------
// Wave-per-node. ubf is packed bf16 (viewed as u32). 4 waves / block.

// Stage 1: 256-wide gather (z||r), epilogue: z=sig(.), rh=sig(.)*h
__global__ __launch_bounds__(256)
void k_agg_act1(const unsigned int* __restrict__ ubf,   // [N][128] u32 = 256 bf16
                const float* __restrict__ hl,
                const int2* __restrict__ epk,
                const int* __restrict__ rowptr,
                const float* __restrict__ dinv,
                const float* __restrict__ bxz, const float* __restrict__ bhz,
                const float* __restrict__ bxr, const float* __restrict__ bhr,
                float* __restrict__ zbuf, float* __restrict__ rhbuf, int N) {
  __shared__ int2 se[4][64];
  int wv = threadIdx.x >> 6;
  int l = threadIdx.x & 63;
  int n = blockIdx.x * 4 + wv;
  if (n >= N) return;

  float dv = dinv[n];
  float w0 = dv * dv;
  const unsigned int* up = ubf + (size_t)n * 128 + l * 2;
  uint2 sv = *(const uint2*)up;
  float a0 = w0 * bf_lo(sv.x);
  float a1 = w0 * bf_hi(sv.x);
  float a2 = w0 * bf_lo(sv.y);
  float a3 = w0 * bf_hi(sv.y);

  int e0 = rowptr[n], e1 = rowptr[n + 1];
  for (int base = e0; base < e1; base += 64) {
    int m = min(64, e1 - base);
    if (l < m) se[wv][l] = epk[base + l];
    __builtin_amdgcn_wave_barrier();
#pragma unroll 4
    for (int j = 0; j < m; ++j) {
      int2 e = se[wv][j];
      float nm = __int_as_float(e.y);
      uint2 v = *(const uint2*)(ubf + (size_t)e.x * 128 + l * 2);
      a0 += nm * bf_lo(v.x);
      a1 += nm * bf_hi(v.x);
      a2 += nm * bf_lo(v.y);
      a3 += nm * bf_hi(v.y);
    }
    __builtin_amdgcn_wave_barrier();
  }

  int c = l * 4;
  if (c < 128) {
    float4 o;
    o.x = sigf(a0 + bxz[c + 0] + bhz[c + 0]);
    o.y = sigf(a1 + bxz[c + 1] + bhz[c + 1]);
    o.z = sigf(a2 + bxz[c + 2] + bhz[c + 2]);
    o.w = sigf(a3 + bxz[c + 3] + bhz[c + 3]);
    *(float4*)&zbuf[(size_t)n * D128 + c] = o;
  } else {
    int cc = c - 128;
    float4 hv = *(const float4*)&hl[(size_t)n * D128 + cc];
    float4 o;
    o.x = sigf(a0 + bxr[cc + 0] + bhr[cc + 0]) * hv.x;
    o.y = sigf(a1 + bxr[cc + 1] + bhr[cc + 1]) * hv.y;
    o.z = sigf(a2 + bxr[cc + 2] + bhr[cc + 2]) * hv.z;
    o.w = sigf(a3 + bxr[cc + 3] + bhr[cc + 3]) * hv.w;
    *(float4*)&rhbuf[(size_t)n * D128 + cc] = o;
  }
}

// Stage 2: 128-wide gather (h~), epilogue: ho = z*h + (1-z)*tanh(.)
__global__ __launch_bounds__(256)
void k_agg_act2(const unsigned int* __restrict__ ubf,   // [N][64] u32 = 128 bf16
                const float* __restrict__ hl,
                const int2* __restrict__ epk,
                const int* __restrict__ rowptr,
                const float* __restrict__ dinv,
                const float* __restrict__ bxh, const float* __restrict__ bhh,
                const float* __restrict__ zbuf,
                float* __restrict__ out, int N) {
  __shared__ int2 se[4][64];
  int wv = threadIdx.x >> 6;
  int l = threadIdx.x & 63;
  int n = blockIdx.x * 4 + wv;
  if (n >= N) return;

  float dv = dinv[n];
  float w0 = dv * dv;
  unsigned int sv = ubf[(size_t)n * 64 + l];
  float a0 = w0 * bf_lo(sv);
  float a1 = w0 * bf_hi(sv);

  int e0 = rowptr[n], e1 = rowptr[n + 1];
  for (int base = e0; base < e1; base += 64) {
    int m = min(64, e1 - base);
    if (l < m) se[wv][l] = epk[base + l];
    __builtin_amdgcn_wave_barrier();
#pragma unroll 4
    for (int j = 0; j < m; ++j) {
      int2 e = se[wv][j];
      float nm = __int_as_float(e.y);
      unsigned int v = ubf[(size_t)e.x * 64 + l];
      a0 += nm * bf_lo(v);
      a1 += nm * bf_hi(v);
    }
    __builtin_amdgcn_wave_barrier();
  }

  int c = l * 2;
  float2 hv = *(const float2*)&hl[(size_t)n * D128 + c];
  float2 zz = *(const float2*)&zbuf[(size_t)n * D128 + c];
  float ht0 = tanhf(a0 + bxh[c + 0] + bhh[c + 0]);
  float ht1 = tanhf(a1 + bxh[c + 1] + bhh[c + 1]);
  float2 o;
  o.x = zz.x * hv.x + (1.0f - zz.x) * ht0;
  o.y = zz.y * hv.y + (1.0f - zz.y) * ht1;
  *(float2*)&out[(size_t)n * D128 + c] = o;
}

// ---------------- host ----------------

static inline char* align16(char* p) {
  return (char*)(((uintptr_t)p + 15) & ~(uintptr_t)15);
}

extern "C" void kernel_launch(void* const* d_in, const int* in_sizes, int n_in,
                              void* d_out, int out_size, void* d_ws, size_t ws_size,
                              hipStream_t stream) {
  const float* x = (const float*)d_in[0];
  const int* ei = (const int*)d_in[1];
  const float* ew = (const float*)d_in[2];
  const float* h = (const float*)d_in[3];
  const float* Wxz = (const float*)d_in[4];
  const float* bxz = (const float*)d_in[5];
  const float* Whz = (const float*)d_in[6];
  const float* bhz = (const float*)d_in[7];
  const float* Wxr = (const float*)d_in[8];
  const float* bxr = (const float*)d_in[9];
  const float* Whr = (const float*)d_in[10];
  const float* bhr = (const float*)d_in[11];
  const float* Wxh = (const float*)d_in[12];
  const float* bxh = (const float*)d_in[13];
  const float* Whh = (const float*)d_in[14];
  const float* bhh = (const float*)d_in[15];
  float* out = (float*)d_out;

  const int N = in_sizes[0] / D128;
  const int E = in_sizes[2];
  const int L = in_sizes[3] / (N * D128);

  char* w = (char*)d_ws;
  float* dinv = (float*)w;  w += (size_t)N * 4;        w = align16(w);
  int* cnt = (int*)w;       w += (size_t)N * 4;        w = align16(w);
  int* rowptr = (int*)w;    w += (size_t)(N + 1) * 4;  w = align16(w);
  int* cursor = (int*)w;    w += (size_t)N * 4;        w = align16(w);
  int* bsum = (int*)w;      w += 64 * 4;               w = align16(w);
  int2* epk = (int2*)w;     w += (size_t)E * 8;        w = align16(w);
  unsigned int* bufA = (unsigned int*)w;               // bf16 gemm out (<=N*256*2B)
  unsigned short* bufA_h = (unsigned short*)w;
  w += (size_t)N * 256 * 2; w = align16(w);
  float* zbuf = (float*)w;  w += (size_t)N * D128 * 4; w = align16(w);
  float* rhbuf = (float*)w; w += (size_t)N * D128 * 4; w = align16(w);

  int gN = (N + 255) / 256;
  int gE = (E + 255) / 256;
  int nScanBlk = (N + 1023) / 1024;
  int gGemm = (N + 127) / 128;
  int gAgg = (N + 3) / 4;

  k_init<<<gN, 256, 0, stream>>>(dinv, cnt, cursor, N);
  k_deg_hist<<<gE, 256, 0, stream>>>(ei, ew, dinv, cnt, E);
  k_dinv<<<gN, 256, 0, stream>>>(dinv, N);
  k_scan1<<<nScanBlk, 256, 0, stream>>>(cnt, rowptr, bsum, N);
  k_scan2<<<1, 64, 0, stream>>>(bsum, nScanBlk);
  k_scan3<<<gN, 256, 0, stream>>>(rowptr, bsum, N, E);
  k_scatter<<<gE, 256, 0, stream>>>(ei, ew, dinv, rowptr, cursor, epk, E);

  const float* xin = x;
  for (int l = 0; l < L; ++l) {
    const float* hl = h + (size_t)l * N * D128;
    const float* Wxz_l = Wxz + (size_t)l * D128 * D128;
    const float* Whz_l = Whz + (size_t)l * D128 * D128;
    const float* Wxr_l = Wxr + (size_t)l * D128 * D128;
    const float* Whr_l = Whr + (size_t)l * D128 * D128;
    const float* Wxh_l = Wxh + (size_t)l * D128 * D128;
    const float* Whh_l = Whh + (size_t)l * D128 * D128;
    const float* bxz_l = bxz + (size_t)l * D128;
    const float* bhz_l = bhz + (size_t)l * D128;
    const float* bxr_l = bxr + (size_t)l * D128;
    const float* bhr_l = bhr + (size_t)l * D128;
    const float* bxh_l = bxh + (size_t)l * D128;
    const float* bhh_l = bhh + (size_t)l * D128;

    // stage 1: u = [xin@Wxz+hl@Whz | xin@Wxr+hl@Whr] -> bf16, then agg+act1
    k_gemm_pair<<<gGemm, 256, 0, stream>>>(xin, hl, Wxz_l, Whz_l, bufA_h, 256, 0, N);
    k_gemm_pair<<<gGemm, 256, 0, stream>>>(xin, hl, Wxr_l, Whr_l, bufA_h, 256, 128, N);
    k_agg_act1<<<gAgg, 256, 0, stream>>>(bufA, hl, epk, rowptr, dinv,
                                         bxz_l, bhz_l, bxr_l, bhr_l, zbuf, rhbuf, N);

    // stage 2: v = xin@Wxh + (r*h)@Whh -> bf16, then agg+act2 -> ho
    k_gemm_pair<<<gGemm, 256, 0, stream>>>(xin, rhbuf, Wxh_l, Whh_l, bufA_h, 128, 0, N);
    float* ho = out + (size_t)l * N * D128;
    k_agg_act2<<<gAgg, 256, 0, stream>>>(bufA, hl, epk, rowptr, dinv,
                                         bxh_l, bhh_l, zbuf, ho, N);
    xin = ho;
  }
}

// Round 8
// 850.141 us; speedup vs baseline: 1.9739x; 1.3114x over previous
//
#include <hip/hip_runtime.h>
#include <cstdint>

#define D128 128

typedef __attribute__((ext_vector_type(8))) short bf16x8;
typedef __attribute__((ext_vector_type(4))) float f32x4;

// ---------------- helpers ----------------

static __device__ __forceinline__ unsigned short f2bf(float x) {
  unsigned int u = __float_as_uint(x);
  unsigned int r = (u + 0x7FFFu + ((u >> 16) & 1u)) >> 16;
  return (unsigned short)r;
}
static __device__ __forceinline__ float bf2f(unsigned short h) {
  return __uint_as_float((unsigned int)h << 16);
}
static __device__ __forceinline__ float bf_lo(unsigned int v) {
  return __uint_as_float(v << 16);
}
static __device__ __forceinline__ float bf_hi(unsigned int v) {
  return __uint_as_float(v & 0xFFFF0000u);
}
static __device__ __forceinline__ float sigf(float x) {
  return 1.0f / (1.0f + __expf(-x));
}
static __device__ __forceinline__ bf16x8 lds_load8(const unsigned short* p) {
  union { unsigned long long q[2]; bf16x8 v; } u;
  u.q[0] = *(const unsigned long long*)p;
  u.q[1] = *(const unsigned long long*)(p + 4);
  return u.v;
}

#define FIXSCALE 8388608.0f  // 2^23

// ---------------- graph prep ----------------

__global__ void k_init(unsigned long long* __restrict__ packed, int n) {
  int i = blockIdx.x * blockDim.x + threadIdx.x;
  if (i < n) packed[i] = 0ULL;
}

// one u64 atomic per edge: hi32 = count (returned value = rank), lo32 = fixed-point deg
__global__ void k_passA(const int* __restrict__ ei, const float* __restrict__ ew,
                        unsigned long long* __restrict__ packed,
                        int* __restrict__ rank, int E) {
  int e = blockIdx.x * blockDim.x + threadIdx.x;
  if (e >= E) return;
  int c = ei[E + e];
  unsigned int fw = (unsigned int)(ew[e] * FIXSCALE + 0.5f);
  unsigned long long old =
      atomicAdd(&packed[c], (1ULL << 32) | (unsigned long long)fw);
  rank[e] = (int)(old >> 32);
}

__global__ void k_dinv(const unsigned long long* __restrict__ packed,
                       float* __restrict__ dinv, int n) {
  int i = blockIdx.x * blockDim.x + threadIdx.x;
  if (i < n) {
    float deg = 1.0f + (float)(unsigned int)(packed[i] & 0xFFFFFFFFu) / FIXSCALE;
    dinv[i] = rsqrtf(deg);
  }
}

// exclusive scan of cnt (= packed>>32) -> rowptr
__global__ void k_scan1(const unsigned long long* __restrict__ packed,
                        int* __restrict__ out, int* __restrict__ bsum, int n) {
  __shared__ int s[256];
  int t = threadIdx.x;
  int base = blockIdx.x * 1024 + t * 4;
  int c0 = (base + 0 < n) ? (int)(packed[base + 0] >> 32) : 0;
  int c1 = (base + 1 < n) ? (int)(packed[base + 1] >> 32) : 0;
  int c2 = (base + 2 < n) ? (int)(packed[base + 2] >> 32) : 0;
  int c3 = (base + 3 < n) ? (int)(packed[base + 3] >> 32) : 0;
  int tot = c0 + c1 + c2 + c3;
  s[t] = tot;
  __syncthreads();
  for (int off = 1; off < 256; off <<= 1) {
    int v = (t >= off) ? s[t - off] : 0;
    __syncthreads();
    s[t] += v;
    __syncthreads();
  }
  int excl = (t == 0) ? 0 : s[t - 1];
  if (base + 0 < n) out[base + 0] = excl;
  if (base + 1 < n) out[base + 1] = excl + c0;
  if (base + 2 < n) out[base + 2] = excl + c0 + c1;
  if (base + 3 < n) out[base + 3] = excl + c0 + c1 + c2;
  if (t == 255) bsum[blockIdx.x] = s[255];
}

__global__ void k_scan2(int* __restrict__ bsum, int nb) {
  __shared__ int s[64];
  int t = threadIdx.x;
  if (t < nb) s[t] = bsum[t];
  __syncthreads();
  if (t == 0) {
    int acc = 0;
    for (int i = 0; i < nb; ++i) { int v = s[i]; s[i] = acc; acc += v; }
  }
  __syncthreads();
  if (t < nb) bsum[t] = s[t];
}

__global__ void k_scan3(int* __restrict__ rowptr, const int* __restrict__ bsum,
                        int n, int E) {
  int i = blockIdx.x * blockDim.x + threadIdx.x;
  if (i < n) rowptr[i] += bsum[i >> 10];
  if (i == 0) rowptr[n] = E;
}

// no atomics: slot = rowptr[target] + rank.  epk = {src, dinv[src]*w}
__global__ void k_passB(const int* __restrict__ ei, const float* __restrict__ ew,
                        const float* __restrict__ dinv, const int* __restrict__ rowptr,
                        const int* __restrict__ rank, int2* __restrict__ epk, int E) {
  int e = blockIdx.x * blockDim.x + threadIdx.x;
  if (e >= E) return;
  int r = ei[e];
  int c = ei[E + e];
  int p = rowptr[c] + rank[e];
  float nm = dinv[r] * ew[e];
  epk[p] = make_int2(r, __float_as_int(nm));
}

// ---------------- MFMA GEMM: C[:, coff:coff+128] = A0@B0 + A1@B1 (bf16 out) --
// A0,A1: [nrows x 128] fp32 row-major. B0,B1: [128 x 128] fp32 row-major.
// Split-precision: A = Ahi + Alo (bf16 pair), B = Bhi + Blo;
// C ~= Ahi*Bhi + Alo*Bhi + Ahi*Blo  (error ~2^-17, effectively fp32).
// Fragment k-map: lane-group g = lane>>4 covers k = g*8..g*8+7 for BOTH A and B
// (any common k-permutation is MFMA-invariant since A/B layouts are symmetric).
// BM=BN=128, BK=32, 4 waves (2x2 of 64x64), 16x16x32 MFMA.

#define GSTRIDE 44    // LDS staging row stride in bf16 elems (88 B)
#define GBUF 5632     // 128 * 44
#define CSTRIDE 136   // epilogue LDS stride

__global__ __launch_bounds__(256)
void k_gemm_pair_mfma(const float* __restrict__ A0, const float* __restrict__ A1,
                      const float* __restrict__ B0, const float* __restrict__ B1,
                      unsigned short* __restrict__ C, int cstride, int coff, int nrows) {
  __shared__ unsigned short lds[4 * GBUF];  // 45056 B
  unsigned short* Ahi = lds;
  unsigned short* Alo = lds + GBUF;
  unsigned short* Bhi = lds + 2 * GBUF;
  unsigned short* Blo = lds + 3 * GBUF;

  const int t = threadIdx.x;
  const int w = t >> 6;
  const int l = t & 63;
  const int r = l & 15;
  const int g = l >> 4;
  const int wr = (w >> 1) * 64;
  const int wc = (w & 1) * 64;
  const int row0 = blockIdx.x * 128;

  // staging maps
  const int sa_row = t >> 1;            // 0..127
  const int sa_k = (t & 1) * 16;        // 0 or 16
  const int sb_k = (t & 15) * 2;        // 0..30 (k pair)
  const int sb_n = (t >> 4) * 8;        // 0..120

  f32x4 acc[4][4];
  const f32x4 zero4 = {0.0f, 0.0f, 0.0f, 0.0f};
#pragma unroll
  for (int i = 0; i < 4; ++i)
#pragma unroll
    for (int j = 0; j < 4; ++j) acc[i][j] = zero4;

  const float* Ap[2] = {A0, A1};
  const float* Bp[2] = {B0, B1};

  for (int s = 0; s < 2; ++s) {
    const float* A = Ap[s];
    const float* B = Bp[s];
    for (int kt = 0; kt < 128; kt += 32) {
      __syncthreads();
      // ---- stage A tile [128][32] -> hi/lo bf16 ----
      {
        int grow = row0 + sa_row;
        float v[16];
        if (grow < nrows) {
          const float* ap = &A[(size_t)grow * D128 + kt + sa_k];
#pragma unroll
          for (int q = 0; q < 4; ++q) {
            float4 f = *(const float4*)(ap + q * 4);
            v[q * 4 + 0] = f.x; v[q * 4 + 1] = f.y;
            v[q * 4 + 2] = f.z; v[q * 4 + 3] = f.w;
          }
        } else {
#pragma unroll
          for (int q = 0; q < 16; ++q) v[q] = 0.0f;
        }
        unsigned short hi[16], lo[16];
#pragma unroll
        for (int q = 0; q < 16; ++q) {
          unsigned short hb = f2bf(v[q]);
          hi[q] = hb;
          lo[q] = f2bf(v[q] - bf2f(hb));
        }
        const unsigned long long* hp = (const unsigned long long*)hi;
        const unsigned long long* lp = (const unsigned long long*)lo;
        int off = sa_row * GSTRIDE + sa_k;
#pragma unroll
        for (int q = 0; q < 4; ++q) {
          *(unsigned long long*)&Ahi[off + q * 4] = hp[q];
          *(unsigned long long*)&Alo[off + q * 4] = lp[q];
        }
      }
      // ---- stage B tile [32][128] transposed -> Bs[n][k], hi/lo ----
      {
        const float* bp0 = &B[(size_t)(kt + sb_k) * D128 + sb_n];
        const float* bp1 = bp0 + D128;
        float u0[8], u1[8];
#pragma unroll
        for (int q = 0; q < 2; ++q) {
          float4 f0 = *(const float4*)(bp0 + q * 4);
          float4 f1 = *(const float4*)(bp1 + q * 4);
          u0[q * 4 + 0] = f0.x; u0[q * 4 + 1] = f0.y;
          u0[q * 4 + 2] = f0.z; u0[q * 4 + 3] = f0.w;
          u1[q * 4 + 0] = f1.x; u1[q * 4 + 1] = f1.y;
          u1[q * 4 + 2] = f1.z; u1[q * 4 + 3] = f1.w;
        }
#pragma unroll
        for (int q = 0; q < 8; ++q) {
          unsigned short h0 = f2bf(u0[q]);
          unsigned short h1 = f2bf(u1[q]);
          unsigned short l0 = f2bf(u0[q] - bf2f(h0));
          unsigned short l1 = f2bf(u1[q] - bf2f(h1));
          int off = (sb_n + q) * GSTRIDE + sb_k;
          *(unsigned int*)&Bhi[off] = (unsigned int)h0 | ((unsigned int)h1 << 16);
          *(unsigned int*)&Blo[off] = (unsigned int)l0 | ((unsigned int)l1 << 16);
        }
      }
      __syncthreads();
      // ---- fragments + MFMA ----
      bf16x8 afh[4], afl[4], bfh[4], bfl[4];
#pragma unroll
      for (int i = 0; i < 4; ++i) {
        int off = (wr + i * 16 + r) * GSTRIDE + g * 8;
        afh[i] = lds_load8(&Ahi[off]);
        afl[i] = lds_load8(&Alo[off]);
      }
#pragma unroll
      for (int j = 0; j < 4; ++j) {
        int off = (wc + j * 16 + r) * GSTRIDE + g * 8;
        bfh[j] = lds_load8(&Bhi[off]);
        bfl[j] = lds_load8(&Blo[off]);
      }
#pragma unroll
      for (int i = 0; i < 4; ++i)
#pragma unroll
        for (int j = 0; j < 4; ++j) {
          acc[i][j] = __builtin_amdgcn_mfma_f32_16x16x32_bf16(afh[i], bfh[j], acc[i][j], 0, 0, 0);
          acc[i][j] = __builtin_amdgcn_mfma_f32_16x16x32_bf16(afl[i], bfh[j], acc[i][j], 0, 0, 0);
          acc[i][j] = __builtin_amdgcn_mfma_f32_16x16x32_bf16(afh[i], bfl[j], acc[i][j], 0, 0, 0);
        }
    }
  }

  // ---- epilogue: LDS bounce, coalesced bf16 row writes ----
  __syncthreads();
  // C/D layout (verified): col = lane&15, row = (lane>>4)*4 + reg
#pragma unroll
  for (int i = 0; i < 4; ++i)
#pragma unroll
    for (int j = 0; j < 4; ++j)
#pragma unroll
      for (int q = 0; q < 4; ++q) {
        int rr = wr + i * 16 + g * 4 + q;
        int cc = wc + j * 16 + r;
        lds[rr * CSTRIDE + cc] = f2bf(acc[i][j][q]);
      }
  __syncthreads();
  {
    int orow = row0 + (t >> 1);
    if (orow < nrows) {
      int half = (t & 1) * 64;
      const unsigned short* src = &lds[(t >> 1) * CSTRIDE + half];
      unsigned short* dst = &C[(size_t)orow * cstride + coff + half];
#pragma unroll
      for (int q = 0; q < 8; ++q)
        *(uint4*)(dst + q * 8) = *(const uint4*)(src + q * 8);
    }
  }
}

// ---------------- fused aggregation + activation ----------------
// Wave-per-node; epk norm excludes dinv[target] (applied in epilogue as dv).

__global__ __launch_bounds__(256)
void k_agg_act1(const unsigned int* __restrict__ ubf,   // [N][128] u32 = 256 bf16
                const float* __restrict__ hl,
                const int2* __restrict__ epk,
                const int* __restrict__ rowptr,
                const float* __restrict__ dinv,
                const float* __restrict__ bxz, const float* __restrict__ bhz,
                const float* __restrict__ bxr, const float* __restrict__ bhr,
                float* __restrict__ zbuf, float* __restrict__ rhbuf, int N) {
  __shared__ int2 se[4][64];
  int wv = threadIdx.x >> 6;
  int l = threadIdx.x & 63;
  int n = blockIdx.x * 4 + wv;
  if (n >= N) return;

  float dv = dinv[n];
  const unsigned int* up = ubf + (size_t)n * 128 + l * 2;
  uint2 sv = *(const uint2*)up;
  float a0 = dv * bf_lo(sv.x);
  float a1 = dv * bf_hi(sv.x);
  float a2 = dv * bf_lo(sv.y);
  float a3 = dv * bf_hi(sv.y);

  int e0 = rowptr[n], e1 = rowptr[n + 1];
  for (int base = e0; base < e1; base += 64) {
    int m = min(64, e1 - base);
    if (l < m) se[wv][l] = epk[base + l];
    __builtin_amdgcn_wave_barrier();
#pragma unroll 4
    for (int j = 0; j < m; ++j) {
      int2 e = se[wv][j];
      float nm = __int_as_float(e.y);
      uint2 v = *(const uint2*)(ubf + (size_t)e.x * 128 + l * 2);
      a0 += nm * bf_lo(v.x);
      a1 += nm * bf_hi(v.x);
      a2 += nm * bf_lo(v.y);
      a3 += nm * bf_hi(v.y);
    }
    __builtin_amdgcn_wave_barrier();
  }
  a0 *= dv; a1 *= dv; a2 *= dv; a3 *= dv;

  int c = l * 4;
  if (c < 128) {
    float4 o;
    o.x = sigf(a0 + bxz[c + 0] + bhz[c + 0]);
    o.y = sigf(a1 + bxz[c + 1] + bhz[c + 1]);
    o.z = sigf(a2 + bxz[c + 2] + bhz[c + 2]);
    o.w = sigf(a3 + bxz[c + 3] + bhz[c + 3]);
    *(float4*)&zbuf[(size_t)n * D128 + c] = o;
  } else {
    int cc = c - 128;
    float4 hv = *(const float4*)&hl[(size_t)n * D128 + cc];
    float4 o;
    o.x = sigf(a0 + bxr[cc + 0] + bhr[cc + 0]) * hv.x;
    o.y = sigf(a1 + bxr[cc + 1] + bhr[cc + 1]) * hv.y;
    o.z = sigf(a2 + bxr[cc + 2] + bhr[cc + 2]) * hv.z;
    o.w = sigf(a3 + bxr[cc + 3] + bhr[cc + 3]) * hv.w;
    *(float4*)&rhbuf[(size_t)n * D128 + cc] = o;
  }
}

__global__ __launch_bounds__(256)
void k_agg_act2(const unsigned int* __restrict__ ubf,   // [N][64] u32 = 128 bf16
                const float* __restrict__ hl,
                const int2* __restrict__ epk,
                const int* __restrict__ rowptr,
                const float* __restrict__ dinv,
                const float* __restrict__ bxh, const float* __restrict__ bhh,
                const float* __restrict__ zbuf,
                float* __restrict__ out, int N) {
  __shared__ int2 se[4][64];
  int wv = threadIdx.x >> 6;
  int l = threadIdx.x & 63;
  int n = blockIdx.x * 4 + wv;
  if (n >= N) return;

  float dv = dinv[n];
  unsigned int sv = ubf[(size_t)n * 64 + l];
  float a0 = dv * bf_lo(sv);
  float a1 = dv * bf_hi(sv);

  int e0 = rowptr[n], e1 = rowptr[n + 1];
  for (int base = e0; base < e1; base += 64) {
    int m = min(64, e1 - base);
    if (l < m) se[wv][l] = epk[base + l];
    __builtin_amdgcn_wave_barrier();
#pragma unroll 4
    for (int j = 0; j < m; ++j) {
      int2 e = se[wv][j];
      float nm = __int_as_float(e.y);
      unsigned int v = ubf[(size_t)e.x * 64 + l];
      a0 += nm * bf_lo(v);
      a1 += nm * bf_hi(v);
    }
    __builtin_amdgcn_wave_barrier();
  }
  a0 *= dv; a1 *= dv;

  int c = l * 2;
  float2 hv = *(const float2*)&hl[(size_t)n * D128 + c];
  float2 zz = *(const float2*)&zbuf[(size_t)n * D128 + c];
  float ht0 = tanhf(a0 + bxh[c + 0] + bhh[c + 0]);
  float ht1 = tanhf(a1 + bxh[c + 1] + bhh[c + 1]);
  float2 o;
  o.x = zz.x * hv.x + (1.0f - zz.x) * ht0;
  o.y = zz.y * hv.y + (1.0f - zz.y) * ht1;
  *(float2*)&out[(size_t)n * D128 + c] = o;
}

// ---------------- host ----------------

static inline char* align16(char* p) {
  return (char*)(((uintptr_t)p + 15) & ~(uintptr_t)15);
}

extern "C" void kernel_launch(void* const* d_in, const int* in_sizes, int n_in,
                              void* d_out, int out_size, void* d_ws, size_t ws_size,
                              hipStream_t stream) {
  const float* x = (const float*)d_in[0];
  const int* ei = (const int*)d_in[1];
  const float* ew = (const float*)d_in[2];
  const float* h = (const float*)d_in[3];
  const float* Wxz = (const float*)d_in[4];
  const float* bxz = (const float*)d_in[5];
  const float* Whz = (const float*)d_in[6];
  const float* bhz = (const float*)d_in[7];
  const float* Wxr = (const float*)d_in[8];
  const float* bxr = (const float*)d_in[9];
  const float* Whr = (const float*)d_in[10];
  const float* bhr = (const float*)d_in[11];
  const float* Wxh = (const float*)d_in[12];
  const float* bxh = (const float*)d_in[13];
  const float* Whh = (const float*)d_in[14];
  const float* bhh = (const float*)d_in[15];
  float* out = (float*)d_out;

  const int N = in_sizes[0] / D128;
  const int E = in_sizes[2];
  const int L = in_sizes[3] / (N * D128);

  char* w = (char*)d_ws;
  unsigned long long* packed = (unsigned long long*)w; w += (size_t)N * 8; w = align16(w);
  float* dinv = (float*)w;  w += (size_t)N * 4;        w = align16(w);
  int* rowptr = (int*)w;    w += (size_t)(N + 1) * 4;  w = align16(w);
  int* bsum = (int*)w;      w += 64 * 4;               w = align16(w);
  int* rank = (int*)w;      w += (size_t)E * 4;        w = align16(w);
  int2* epk = (int2*)w;     w += (size_t)E * 8;        w = align16(w);
  unsigned int* bufA = (unsigned int*)w;
  unsigned short* bufA_h = (unsigned short*)w;
  w += (size_t)N * 256 * 2; w = align16(w);
  float* zbuf = (float*)w;  w += (size_t)N * D128 * 4; w = align16(w);
  float* rhbuf = (float*)w; w += (size_t)N * D128 * 4; w = align16(w);

  int gN = (N + 255) / 256;
  int gE = (E + 255) / 256;
  int nScanBlk = (N + 1023) / 1024;
  int gGemm = (N + 127) / 128;
  int gAgg = (N + 3) / 4;

  k_init<<<gN, 256, 0, stream>>>(packed, N);
  k_passA<<<gE, 256, 0, stream>>>(ei, ew, packed, rank, E);
  k_dinv<<<gN, 256, 0, stream>>>(packed, dinv, N);
  k_scan1<<<nScanBlk, 256, 0, stream>>>(packed, rowptr, bsum, N);
  k_scan2<<<1, 64, 0, stream>>>(bsum, nScanBlk);
  k_scan3<<<gN, 256, 0, stream>>>(rowptr, bsum, N, E);
  k_passB<<<gE, 256, 0, stream>>>(ei, ew, dinv, rowptr, rank, epk, E);

  const float* xin = x;
  for (int l = 0; l < L; ++l) {
    const float* hl = h + (size_t)l * N * D128;
    const float* Wxz_l = Wxz + (size_t)l * D128 * D128;
    const float* Whz_l = Whz + (size_t)l * D128 * D128;
    const float* Wxr_l = Wxr + (size_t)l * D128 * D128;
    const float* Whr_l = Whr + (size_t)l * D128 * D128;
    const float* Wxh_l = Wxh + (size_t)l * D128 * D128;
    const float* Whh_l = Whh + (size_t)l * D128 * D128;
    const float* bxz_l = bxz + (size_t)l * D128;
    const float* bhz_l = bhz + (size_t)l * D128;
    const float* bxr_l = bxr + (size_t)l * D128;
    const float* bhr_l = bhr + (size_t)l * D128;
    const float* bxh_l = bxh + (size_t)l * D128;
    const float* bhh_l = bhh + (size_t)l * D128;

    k_gemm_pair_mfma<<<gGemm, 256, 0, stream>>>(xin, hl, Wxz_l, Whz_l, bufA_h, 256, 0, N);
    k_gemm_pair_mfma<<<gGemm, 256, 0, stream>>>(xin, hl, Wxr_l, Whr_l, bufA_h, 256, 128, N);
    k_agg_act1<<<gAgg, 256, 0, stream>>>(bufA, hl, epk, rowptr, dinv,
                                         bxz_l, bhz_l, bxr_l, bhr_l, zbuf, rhbuf, N);

    k_gemm_pair_mfma<<<gGemm, 256, 0, stream>>>(xin, rhbuf, Wxh_l, Whh_l, bufA_h, 128, 0, N);
    float* ho = out + (size_t)l * N * D128;
    k_agg_act2<<<gAgg, 256, 0, stream>>>(bufA, hl, epk, rowptr, dinv,
                                         bxh_l, bhh_l, zbuf, ho, N);
    xin = ho;
  }
}

// Round 9
// 745.494 us; speedup vs baseline: 2.2510x; 1.1404x over previous
//
#include <hip/hip_runtime.h>
#include <cstdint>

#define D128 128

typedef __attribute__((ext_vector_type(8))) short bf16x8;
typedef __attribute__((ext_vector_type(4))) float f32x4;

// ---------------- helpers ----------------

static __device__ __forceinline__ unsigned short f2bf(float x) {
  unsigned int u = __float_as_uint(x);
  unsigned int r = (u + 0x7FFFu + ((u >> 16) & 1u)) >> 16;
  return (unsigned short)r;
}
static __device__ __forceinline__ float bf2f(unsigned short h) {
  return __uint_as_float((unsigned int)h << 16);
}
static __device__ __forceinline__ float bf_lo(unsigned int v) {
  return __uint_as_float(v << 16);
}
static __device__ __forceinline__ float bf_hi(unsigned int v) {
  return __uint_as_float(v & 0xFFFF0000u);
}
static __device__ __forceinline__ float sigf(float x) {
  return 1.0f / (1.0f + __expf(-x));
}
static __device__ __forceinline__ bf16x8 lds_load8(const unsigned short* p) {
  union { unsigned long long q[2]; bf16x8 v; } u;
  u.q[0] = *(const unsigned long long*)p;
  u.q[1] = *(const unsigned long long*)(p + 4);
  return u.v;
}

#define FIXSCALE 8388608.0f  // 2^23

// ---------------- graph prep ----------------

__global__ void k_init(unsigned long long* __restrict__ packed, int n) {
  int i = blockIdx.x * blockDim.x + threadIdx.x;
  if (i < n) packed[i] = 0ULL;
}

__global__ void k_passA(const int* __restrict__ ei, const float* __restrict__ ew,
                        unsigned long long* __restrict__ packed,
                        int* __restrict__ rank, int E) {
  int e = blockIdx.x * blockDim.x + threadIdx.x;
  if (e >= E) return;
  int c = ei[E + e];
  unsigned int fw = (unsigned int)(ew[e] * FIXSCALE + 0.5f);
  unsigned long long old =
      atomicAdd(&packed[c], (1ULL << 32) | (unsigned long long)fw);
  rank[e] = (int)(old >> 32);
}

__global__ void k_dinv(const unsigned long long* __restrict__ packed,
                       float* __restrict__ dinv, int n) {
  int i = blockIdx.x * blockDim.x + threadIdx.x;
  if (i < n) {
    float deg = 1.0f + (float)(unsigned int)(packed[i] & 0xFFFFFFFFu) / FIXSCALE;
    dinv[i] = rsqrtf(deg);
  }
}

__global__ void k_scan1(const unsigned long long* __restrict__ packed,
                        int* __restrict__ out, int* __restrict__ bsum, int n) {
  __shared__ int s[256];
  int t = threadIdx.x;
  int base = blockIdx.x * 1024 + t * 4;
  int c0 = (base + 0 < n) ? (int)(packed[base + 0] >> 32) : 0;
  int c1 = (base + 1 < n) ? (int)(packed[base + 1] >> 32) : 0;
  int c2 = (base + 2 < n) ? (int)(packed[base + 2] >> 32) : 0;
  int c3 = (base + 3 < n) ? (int)(packed[base + 3] >> 32) : 0;
  int tot = c0 + c1 + c2 + c3;
  s[t] = tot;
  __syncthreads();
  for (int off = 1; off < 256; off <<= 1) {
    int v = (t >= off) ? s[t - off] : 0;
    __syncthreads();
    s[t] += v;
    __syncthreads();
  }
  int excl = (t == 0) ? 0 : s[t - 1];
  if (base + 0 < n) out[base + 0] = excl;
  if (base + 1 < n) out[base + 1] = excl + c0;
  if (base + 2 < n) out[base + 2] = excl + c0 + c1;
  if (base + 3 < n) out[base + 3] = excl + c0 + c1 + c2;
  if (t == 255) bsum[blockIdx.x] = s[255];
}

__global__ void k_scan2(int* __restrict__ bsum, int nb) {
  __shared__ int s[64];
  int t = threadIdx.x;
  if (t < nb) s[t] = bsum[t];
  __syncthreads();
  if (t == 0) {
    int acc = 0;
    for (int i = 0; i < nb; ++i) { int v = s[i]; s[i] = acc; acc += v; }
  }
  __syncthreads();
  if (t < nb) bsum[t] = s[t];
}

__global__ void k_scan3(int* __restrict__ rowptr, const int* __restrict__ bsum,
                        int n, int E) {
  int i = blockIdx.x * blockDim.x + threadIdx.x;
  if (i < n) rowptr[i] += bsum[i >> 10];
  if (i == 0) rowptr[n] = E;
}

__global__ void k_passB(const int* __restrict__ ei, const float* __restrict__ ew,
                        const float* __restrict__ dinv, const int* __restrict__ rowptr,
                        const int* __restrict__ rank, int2* __restrict__ epk, int E) {
  int e = blockIdx.x * blockDim.x + threadIdx.x;
  if (e >= E) return;
  int r = ei[e];
  int c = ei[E + e];
  int p = rowptr[c] + rank[e];
  float nm = dinv[r] * ew[e];
  epk[p] = make_int2(r, __float_as_int(nm));
}

// ---------------- MFMA GEMM (split-precision), templated epilogue ----------
// Q=false: bf16 output, cstride in elements. Q=true: int8 output with
// per-(row,128-slice) scale; cstride/coff in BYTES, scale -> scl[row*2+(coff>>7)].

#define GSTRIDE 44
#define GBUF 5632
#define CSTRIDE 136

template <bool Q>
__global__ __launch_bounds__(256)
void k_gemm_pair_mfma(const float* __restrict__ A0, const float* __restrict__ A1,
                      const float* __restrict__ B0, const float* __restrict__ B1,
                      unsigned short* __restrict__ Cb, unsigned char* __restrict__ Cq,
                      float* __restrict__ scl, int cstride, int coff, int nrows) {
  __shared__ unsigned short lds[4 * GBUF];
  unsigned short* Ahi = lds;
  unsigned short* Alo = lds + GBUF;
  unsigned short* Bhi = lds + 2 * GBUF;
  unsigned short* Blo = lds + 3 * GBUF;

  const int t = threadIdx.x;
  const int w = t >> 6;
  const int l = t & 63;
  const int r = l & 15;
  const int g = l >> 4;
  const int wr = (w >> 1) * 64;
  const int wc = (w & 1) * 64;
  const int row0 = blockIdx.x * 128;

  const int sa_row = t >> 1;
  const int sa_k = (t & 1) * 16;
  const int sb_k = (t & 15) * 2;
  const int sb_n = (t >> 4) * 8;

  f32x4 acc[4][4];
  const f32x4 zero4 = {0.0f, 0.0f, 0.0f, 0.0f};
#pragma unroll
  for (int i = 0; i < 4; ++i)
#pragma unroll
    for (int j = 0; j < 4; ++j) acc[i][j] = zero4;

  const float* Ap[2] = {A0, A1};
  const float* Bp[2] = {B0, B1};

  for (int s = 0; s < 2; ++s) {
    const float* A = Ap[s];
    const float* B = Bp[s];
    for (int kt = 0; kt < 128; kt += 32) {
      __syncthreads();
      {
        int grow = row0 + sa_row;
        float v[16];
        if (grow < nrows) {
          const float* ap = &A[(size_t)grow * D128 + kt + sa_k];
#pragma unroll
          for (int q = 0; q < 4; ++q) {
            float4 f = *(const float4*)(ap + q * 4);
            v[q * 4 + 0] = f.x; v[q * 4 + 1] = f.y;
            v[q * 4 + 2] = f.z; v[q * 4 + 3] = f.w;
          }
        } else {
#pragma unroll
          for (int q = 0; q < 16; ++q) v[q] = 0.0f;
        }
        unsigned short hi[16], lo[16];
#pragma unroll
        for (int q = 0; q < 16; ++q) {
          unsigned short hb = f2bf(v[q]);
          hi[q] = hb;
          lo[q] = f2bf(v[q] - bf2f(hb));
        }
        const unsigned long long* hp = (const unsigned long long*)hi;
        const unsigned long long* lp = (const unsigned long long*)lo;
        int off = sa_row * GSTRIDE + sa_k;
#pragma unroll
        for (int q = 0; q < 4; ++q) {
          *(unsigned long long*)&Ahi[off + q * 4] = hp[q];
          *(unsigned long long*)&Alo[off + q * 4] = lp[q];
        }
      }
      {
        const float* bp0 = &B[(size_t)(kt + sb_k) * D128 + sb_n];
        const float* bp1 = bp0 + D128;
        float u0[8], u1[8];
#pragma unroll
        for (int q = 0; q < 2; ++q) {
          float4 f0 = *(const float4*)(bp0 + q * 4);
          float4 f1 = *(const float4*)(bp1 + q * 4);
          u0[q * 4 + 0] = f0.x; u0[q * 4 + 1] = f0.y;
          u0[q * 4 + 2] = f0.z; u0[q * 4 + 3] = f0.w;
          u1[q * 4 + 0] = f1.x; u1[q * 4 + 1] = f1.y;
          u1[q * 4 + 2] = f1.z; u1[q * 4 + 3] = f1.w;
        }
#pragma unroll
        for (int q = 0; q < 8; ++q) {
          unsigned short h0 = f2bf(u0[q]);
          unsigned short h1 = f2bf(u1[q]);
          unsigned short l0 = f2bf(u0[q] - bf2f(h0));
          unsigned short l1 = f2bf(u1[q] - bf2f(h1));
          int off = (sb_n + q) * GSTRIDE + sb_k;
          *(unsigned int*)&Bhi[off] = (unsigned int)h0 | ((unsigned int)h1 << 16);
          *(unsigned int*)&Blo[off] = (unsigned int)l0 | ((unsigned int)l1 << 16);
        }
      }
      __syncthreads();
      bf16x8 afh[4], afl[4], bfh[4], bfl[4];
#pragma unroll
      for (int i = 0; i < 4; ++i) {
        int off = (wr + i * 16 + r) * GSTRIDE + g * 8;
        afh[i] = lds_load8(&Ahi[off]);
        afl[i] = lds_load8(&Alo[off]);
      }
#pragma unroll
      for (int j = 0; j < 4; ++j) {
        int off = (wc + j * 16 + r) * GSTRIDE + g * 8;
        bfh[j] = lds_load8(&Bhi[off]);
        bfl[j] = lds_load8(&Blo[off]);
      }
#pragma unroll
      for (int i = 0; i < 4; ++i)
#pragma unroll
        for (int j = 0; j < 4; ++j) {
          acc[i][j] = __builtin_amdgcn_mfma_f32_16x16x32_bf16(afh[i], bfh[j], acc[i][j], 0, 0, 0);
          acc[i][j] = __builtin_amdgcn_mfma_f32_16x16x32_bf16(afl[i], bfh[j], acc[i][j], 0, 0, 0);
          acc[i][j] = __builtin_amdgcn_mfma_f32_16x16x32_bf16(afh[i], bfl[j], acc[i][j], 0, 0, 0);
        }
    }
  }

  // ---- epilogue: LDS bounce (bf16) ----
  __syncthreads();
#pragma unroll
  for (int i = 0; i < 4; ++i)
#pragma unroll
    for (int j = 0; j < 4; ++j)
#pragma unroll
      for (int q = 0; q < 4; ++q) {
        int rr = wr + i * 16 + g * 4 + q;
        int cc = wc + j * 16 + r;
        lds[rr * CSTRIDE + cc] = f2bf(acc[i][j][q]);
      }
  __syncthreads();
  {
    int orow = row0 + (t >> 1);
    int half = (t & 1) * 64;
    const unsigned short* src = &lds[(t >> 1) * CSTRIDE + half];
    if (!Q) {
      if (orow < nrows) {
        unsigned short* dst = &Cb[(size_t)orow * cstride + coff + half];
#pragma unroll
        for (int q = 0; q < 8; ++q)
          *(uint4*)(dst + q * 8) = *(const uint4*)(src + q * 8);
      }
    } else {
      // per-(row,128-slice) symmetric int8 quant, bias +128
      const unsigned int* sp = (const unsigned int*)src;  // 32 u32 = 64 bf16
      float mx = 0.0f;
#pragma unroll
      for (int q = 0; q < 32; ++q) {
        unsigned int v = sp[q];
        mx = fmaxf(mx, fmaxf(fabsf(bf_lo(v)), fabsf(bf_hi(v))));
      }
      mx = fmaxf(mx, __shfl_xor(mx, 1));
      mx = fmaxf(mx, 1e-12f);
      float s = mx * (1.0f / 127.0f);
      float inv = 127.0f / mx;
      if (orow < nrows) {
        unsigned int ob[16];
#pragma unroll
        for (int q = 0; q < 16; ++q) {
          unsigned int v0 = sp[q * 2];
          unsigned int v1 = sp[q * 2 + 1];
          int q0 = (int)rintf(bf_lo(v0) * inv) + 128;
          int q1 = (int)rintf(bf_hi(v0) * inv) + 128;
          int q2 = (int)rintf(bf_lo(v1) * inv) + 128;
          int q3 = (int)rintf(bf_hi(v1) * inv) + 128;
          ob[q] = (unsigned int)(q0 & 0xFF) | ((unsigned int)(q1 & 0xFF) << 8) |
                  ((unsigned int)(q2 & 0xFF) << 16) | ((unsigned int)(q3 & 0xFF) << 24);
        }
        unsigned char* dst = Cq + (size_t)orow * cstride + coff + half;
#pragma unroll
        for (int q = 0; q < 4; ++q)
          *(uint4*)(dst + q * 16) = *(const uint4*)&ob[q * 4];
        if ((t & 1) == 0) scl[orow * 2 + (coff >> 7)] = s;
      }
    }
  }
}

// ---------------- fused aggregation + activation ----------------

// Stage 1: int8 gather (256 cols as [N][64] u32), per-slice scales in scl[N][2].
__global__ __launch_bounds__(256)
void k_agg_act1(const unsigned int* __restrict__ uq,    // [N][64] u32 = 256 u8
                const float2* __restrict__ scl,         // [N] {s0,s1}
                const float* __restrict__ hl,
                const int2* __restrict__ epk,
                const int* __restrict__ rowptr,
                const float* __restrict__ dinv,
                const float* __restrict__ bxz, const float* __restrict__ bhz,
                const float* __restrict__ bxr, const float* __restrict__ bhr,
                float* __restrict__ zbuf, float* __restrict__ rhbuf, int N) {
  __shared__ int2 se[4][64];
  int wv = threadIdx.x >> 6;
  int l = threadIdx.x & 63;
  int n = blockIdx.x * 4 + wv;
  if (n >= N) return;

  float dv = dinv[n];
  float2 sn = scl[n];
  float sself = (l < 32) ? sn.x : sn.y;
  float w0 = dv * sself;
  unsigned int bs = uq[(size_t)n * 64 + l];
  float a0 = w0 * (float)(bs & 0xFF);
  float a1 = w0 * (float)((bs >> 8) & 0xFF);
  float a2 = w0 * (float)((bs >> 16) & 0xFF);
  float a3 = w0 * (float)(bs >> 24);
  float sumw = w0;

  int e0 = rowptr[n], e1 = rowptr[n + 1];
  for (int base = e0; base < e1; base += 64) {
    int m = min(64, e1 - base);
    if (l < m) se[wv][l] = epk[base + l];
    __builtin_amdgcn_wave_barrier();
#pragma unroll 4
    for (int j = 0; j < m; ++j) {
      int2 e = se[wv][j];
      float nm = __int_as_float(e.y);
      float2 s2 = scl[e.x];
      float ns = nm * ((l < 32) ? s2.x : s2.y);
      unsigned int v = uq[(size_t)e.x * 64 + l];
      a0 += ns * (float)(v & 0xFF);
      a1 += ns * (float)((v >> 8) & 0xFF);
      a2 += ns * (float)((v >> 16) & 0xFF);
      a3 += ns * (float)(v >> 24);
      sumw += ns;
    }
    __builtin_amdgcn_wave_barrier();
  }
  float off = 128.0f * sumw;
  a0 = (a0 - off) * dv;
  a1 = (a1 - off) * dv;
  a2 = (a2 - off) * dv;
  a3 = (a3 - off) * dv;

  int c = l * 4;
  if (c < 128) {
    float4 o;
    o.x = sigf(a0 + bxz[c + 0] + bhz[c + 0]);
    o.y = sigf(a1 + bxz[c + 1] + bhz[c + 1]);
    o.z = sigf(a2 + bxz[c + 2] + bhz[c + 2]);
    o.w = sigf(a3 + bxz[c + 3] + bhz[c + 3]);
    *(float4*)&zbuf[(size_t)n * D128 + c] = o;
  } else {
    int cc = c - 128;
    float4 hv = *(const float4*)&hl[(size_t)n * D128 + cc];
    float4 o;
    o.x = sigf(a0 + bxr[cc + 0] + bhr[cc + 0]) * hv.x;
    o.y = sigf(a1 + bxr[cc + 1] + bhr[cc + 1]) * hv.y;
    o.z = sigf(a2 + bxr[cc + 2] + bhr[cc + 2]) * hv.z;
    o.w = sigf(a3 + bxr[cc + 3] + bhr[cc + 3]) * hv.w;
    *(float4*)&rhbuf[(size_t)n * D128 + cc] = o;
  }
}

// Stage 2: bf16 gather (unchanged).
__global__ __launch_bounds__(256)
void k_agg_act2(const unsigned int* __restrict__ ubf,   // [N][64] u32 = 128 bf16
                const float* __restrict__ hl,
                const int2* __restrict__ epk,
                const int* __restrict__ rowptr,
                const float* __restrict__ dinv,
                const float* __restrict__ bxh, const float* __restrict__ bhh,
                const float* __restrict__ zbuf,
                float* __restrict__ out, int N) {
  __shared__ int2 se[4][64];
  int wv = threadIdx.x >> 6;
  int l = threadIdx.x & 63;
  int n = blockIdx.x * 4 + wv;
  if (n >= N) return;

  float dv = dinv[n];
  unsigned int sv = ubf[(size_t)n * 64 + l];
  float a0 = dv * bf_lo(sv);
  float a1 = dv * bf_hi(sv);

  int e0 = rowptr[n], e1 = rowptr[n + 1];
  for (int base = e0; base < e1; base += 64) {
    int m = min(64, e1 - base);
    if (l < m) se[wv][l] = epk[base + l];
    __builtin_amdgcn_wave_barrier();
#pragma unroll 4
    for (int j = 0; j < m; ++j) {
      int2 e = se[wv][j];
      float nm = __int_as_float(e.y);
      unsigned int v = ubf[(size_t)e.x * 64 + l];
      a0 += nm * bf_lo(v);
      a1 += nm * bf_hi(v);
    }
    __builtin_amdgcn_wave_barrier();
  }
  a0 *= dv; a1 *= dv;

  int c = l * 2;
  float2 hv = *(const float2*)&hl[(size_t)n * D128 + c];
  float2 zz = *(const float2*)&zbuf[(size_t)n * D128 + c];
  float ht0 = tanhf(a0 + bxh[c + 0] + bhh[c + 0]);
  float ht1 = tanhf(a1 + bxh[c + 1] + bhh[c + 1]);
  float2 o;
  o.x = zz.x * hv.x + (1.0f - zz.x) * ht0;
  o.y = zz.y * hv.y + (1.0f - zz.y) * ht1;
  *(float2*)&out[(size_t)n * D128 + c] = o;
}

// ---------------- host ----------------

static inline char* align16(char* p) {
  return (char*)(((uintptr_t)p + 15) & ~(uintptr_t)15);
}

extern "C" void kernel_launch(void* const* d_in, const int* in_sizes, int n_in,
                              void* d_out, int out_size, void* d_ws, size_t ws_size,
                              hipStream_t stream) {
  const float* x = (const float*)d_in[0];
  const int* ei = (const int*)d_in[1];
  const float* ew = (const float*)d_in[2];
  const float* h = (const float*)d_in[3];
  const float* Wxz = (const float*)d_in[4];
  const float* bxz = (const float*)d_in[5];
  const float* Whz = (const float*)d_in[6];
  const float* bhz = (const float*)d_in[7];
  const float* Wxr = (const float*)d_in[8];
  const float* bxr = (const float*)d_in[9];
  const float* Whr = (const float*)d_in[10];
  const float* bhr = (const float*)d_in[11];
  const float* Wxh = (const float*)d_in[12];
  const float* bxh = (const float*)d_in[13];
  const float* Whh = (const float*)d_in[14];
  const float* bhh = (const float*)d_in[15];
  float* out = (float*)d_out;

  const int N = in_sizes[0] / D128;
  const int E = in_sizes[2];
  const int L = in_sizes[3] / (N * D128);

  char* w = (char*)d_ws;
  unsigned long long* packed = (unsigned long long*)w; w += (size_t)N * 8; w = align16(w);
  float* dinv = (float*)w;  w += (size_t)N * 4;        w = align16(w);
  int* rowptr = (int*)w;    w += (size_t)(N + 1) * 4;  w = align16(w);
  int* bsum = (int*)w;      w += 64 * 4;               w = align16(w);
  int* rank = (int*)w;      w += (size_t)E * 4;        w = align16(w);
  int2* epk = (int2*)w;     w += (size_t)E * 8;        w = align16(w);
  unsigned int* uq = (unsigned int*)w;                 // stage1 int8 out [N][64] u32
  unsigned char* uq_b = (unsigned char*)w;
  w += (size_t)N * 256;     w = align16(w);
  float* sclA = (float*)w;  w += (size_t)N * 8;        w = align16(w);  // [N][2]
  unsigned int* bufA = (unsigned int*)w;               // stage2 bf16 out [N][64] u32
  unsigned short* bufA_h = (unsigned short*)w;
  w += (size_t)N * 128 * 2; w = align16(w);
  float* zbuf = (float*)w;  w += (size_t)N * D128 * 4; w = align16(w);
  float* rhbuf = (float*)w; w += (size_t)N * D128 * 4; w = align16(w);

  int gN = (N + 255) / 256;
  int gE = (E + 255) / 256;
  int nScanBlk = (N + 1023) / 1024;
  int gGemm = (N + 127) / 128;
  int gAgg = (N + 3) / 4;

  k_init<<<gN, 256, 0, stream>>>(packed, N);
  k_passA<<<gE, 256, 0, stream>>>(ei, ew, packed, rank, E);
  k_dinv<<<gN, 256, 0, stream>>>(packed, dinv, N);
  k_scan1<<<nScanBlk, 256, 0, stream>>>(packed, rowptr, bsum, N);
  k_scan2<<<1, 64, 0, stream>>>(bsum, nScanBlk);
  k_scan3<<<gN, 256, 0, stream>>>(rowptr, bsum, N, E);
  k_passB<<<gE, 256, 0, stream>>>(ei, ew, dinv, rowptr, rank, epk, E);

  const float* xin = x;
  for (int l = 0; l < L; ++l) {
    const float* hl = h + (size_t)l * N * D128;
    const float* Wxz_l = Wxz + (size_t)l * D128 * D128;
    const float* Whz_l = Whz + (size_t)l * D128 * D128;
    const float* Wxr_l = Wxr + (size_t)l * D128 * D128;
    const float* Whr_l = Whr + (size_t)l * D128 * D128;
    const float* Wxh_l = Wxh + (size_t)l * D128 * D128;
    const float* Whh_l = Whh + (size_t)l * D128 * D128;
    const float* bxz_l = bxz + (size_t)l * D128;
    const float* bhz_l = bhz + (size_t)l * D128;
    const float* bxr_l = bxr + (size_t)l * D128;
    const float* bhr_l = bhr + (size_t)l * D128;
    const float* bxh_l = bxh + (size_t)l * D128;
    const float* bhh_l = bhh + (size_t)l * D128;

    // stage 1: z||r pre-activations -> int8 (per-row-slice scale)
    k_gemm_pair_mfma<true><<<gGemm, 256, 0, stream>>>(
        xin, hl, Wxz_l, Whz_l, nullptr, uq_b, sclA, 256, 0, N);
    k_gemm_pair_mfma<true><<<gGemm, 256, 0, stream>>>(
        xin, hl, Wxr_l, Whr_l, nullptr, uq_b, sclA, 256, 128, N);
    k_agg_act1<<<gAgg, 256, 0, stream>>>(uq, (const float2*)sclA, hl, epk, rowptr, dinv,
                                         bxz_l, bhz_l, bxr_l, bhr_l, zbuf, rhbuf, N);

    // stage 2: h~ pre-activation -> bf16
    k_gemm_pair_mfma<false><<<gGemm, 256, 0, stream>>>(
        xin, rhbuf, Wxh_l, Whh_l, bufA_h, nullptr, nullptr, 128, 0, N);
    float* ho = out + (size_t)l * N * D128;
    k_agg_act2<<<gAgg, 256, 0, stream>>>(bufA, hl, epk, rowptr, dinv,
                                         bxh_l, bhh_l, zbuf, ho, N);
    xin = ho;
  }
}